// Round 13
// baseline (84.701 us; speedup 1.0000x reference)
//
#include <hip/hip_runtime.h>
#include <math.h>

#define EPS 1e-6f

constexpr int B_ = 32;
constexpr int T_ = 8192;
constexpr int F_ = 128;
constexpr int FG = F_ / 4;    // 32 float4 feature-groups per row
constexpr int FH = F_ / 2;    // 64 float2 feature-pairs per row

// fast pow for strictly-positive base
__device__ __forceinline__ float fpow(float b, float e) {
    return exp2f(e * __log2f(b));
}

// -------- pass 1 (unchanged): per-chunk local sums --------
template<int NC>
__global__ __launch_bounds__(256) void pcen_pass1(
    const float4* __restrict__ x4,
    const float*  __restrict__ log_s,
    float4* __restrict__ S4)
{
    constexpr int L = T_ / NC;
    const int fg    = threadIdx.x & 31;
    const int slot  = threadIdx.x >> 5;              // 0..7
    const int cb    = blockIdx.x % (NC / 8);
    const int b     = blockIdx.x / (NC / 8);
    const int chunk = cb * 8 + slot;

    const float4 lsv = reinterpret_cast<const float4*>(log_s)[fg];
    const float s0 = expf(lsv.x), s1 = expf(lsv.y), s2 = expf(lsv.z), s3 = expf(lsv.w);
    const float a0 = 1.f - s0,   a1 = 1.f - s1,    a2 = 1.f - s2,    a3 = 1.f - s3;

    const float4* xp = x4 + ((size_t)b * T_ + (size_t)chunk * L) * FG + fg;

    float c0 = 0.f, c1 = 0.f, c2 = 0.f, c3 = 0.f;
    #pragma unroll
    for (int i = 0; i < L; ++i) {
        const float4 xv = xp[(size_t)i * FG];
        c0 = fmaf(a0, c0, s0 * xv.x);
        c1 = fmaf(a1, c1, s1 * xv.y);
        c2 = fmaf(a2, c2, s2 * xv.z);
        c3 = fmaf(a3, c3, s3 * xv.w);
    }
    S4[((size_t)b * NC + chunk) * FG + fg] = make_float4(c0, c1, c2, c3);
}

// -------- pass 2 (unchanged): serial combine -> carries --------
template<int NC>
__global__ __launch_bounds__(32) void pcen_pass2(
    const float4* __restrict__ state4,
    const float*  __restrict__ log_s,
    const float4* __restrict__ S4,
    float4* __restrict__ carry4,
    float4* __restrict__ new_state4)
{
    constexpr int L = T_ / NC;
    const int fg = threadIdx.x;   // 0..31
    const int b  = blockIdx.x;

    const float4 lsv = reinterpret_cast<const float4*>(log_s)[fg];
    const float aL0 = fpow(1.f - expf(lsv.x), (float)L);
    const float aL1 = fpow(1.f - expf(lsv.y), (float)L);
    const float aL2 = fpow(1.f - expf(lsv.z), (float)L);
    const float aL3 = fpow(1.f - expf(lsv.w), (float)L);

    float4 c = state4[(size_t)b * FG + fg];
    #pragma unroll 8
    for (int k = 0; k < NC; ++k) {
        const size_t idx = ((size_t)b * NC + k) * FG + fg;
        carry4[idx] = c;
        const float4 Sv = S4[idx];
        c.x = fmaf(aL0, c.x, Sv.x);
        c.y = fmaf(aL1, c.y, Sv.y);
        c.z = fmaf(aL2, c.z, Sv.z);
        c.w = fmaf(aL3, c.w, Sv.w);
    }
    new_state4[(size_t)b * FG + fg] = c;
}

// -------- pass 3: float2 lanes, batch-4, sqrt fast-path, occ>=6w/SIMD --------
template<bool RHALF>
__device__ __forceinline__ void p3_loop(
    const float2* __restrict__ xp, float2* __restrict__ yp, int L_steps,
    float2 c,
    float s0, float s1, float a0, float a1,
    float na0, float na1, float d0, float d1,
    float r0, float r1, float dr0, float dr1)
{
    #pragma unroll
    for (int i = 0; i < L_steps; i += 4) {
        float2 xv0 = xp[(size_t)(i + 0) * FH];
        float2 xv1 = xp[(size_t)(i + 1) * FH];
        float2 xv2 = xp[(size_t)(i + 2) * FH];
        float2 xv3 = xp[(size_t)(i + 3) * FH];

        float2 yv0, yv1, yv2, yv3;

        auto yval = [&](float xv, float cc, float na, float d, float r, float dr) {
            const float p = exp2f(na * __log2f(EPS + cc));   // (EPS+E)^-alpha
            const float v = fmaf(xv, p, d);                   // u + delta
            const float t = RHALF ? sqrtf(v) : exp2f(r * __log2f(v));
            return t - dr;
        };

        c.x = fmaf(a0, c.x, s0 * xv0.x);
        c.y = fmaf(a1, c.y, s1 * xv0.y);
        yv0.x = yval(xv0.x, c.x, na0, d0, r0, dr0);
        yv0.y = yval(xv0.y, c.y, na1, d1, r1, dr1);

        c.x = fmaf(a0, c.x, s0 * xv1.x);
        c.y = fmaf(a1, c.y, s1 * xv1.y);
        yv1.x = yval(xv1.x, c.x, na0, d0, r0, dr0);
        yv1.y = yval(xv1.y, c.y, na1, d1, r1, dr1);

        c.x = fmaf(a0, c.x, s0 * xv2.x);
        c.y = fmaf(a1, c.y, s1 * xv2.y);
        yv2.x = yval(xv2.x, c.x, na0, d0, r0, dr0);
        yv2.y = yval(xv2.y, c.y, na1, d1, r1, dr1);

        c.x = fmaf(a0, c.x, s0 * xv3.x);
        c.y = fmaf(a1, c.y, s1 * xv3.y);
        yv3.x = yval(xv3.x, c.x, na0, d0, r0, dr0);
        yv3.y = yval(xv3.y, c.y, na1, d1, r1, dr1);

        yp[(size_t)(i + 0) * FH] = yv0;
        yp[(size_t)(i + 1) * FH] = yv1;
        yp[(size_t)(i + 2) * FH] = yv2;
        yp[(size_t)(i + 3) * FH] = yv3;
    }
}

template<int NC>
__global__ __launch_bounds__(256, 6) void pcen_pass3(
    const float2* __restrict__ x2,
    const float*  __restrict__ log_s,
    const float*  __restrict__ log_alpha,
    const float*  __restrict__ log_delta,
    const float*  __restrict__ log_r,
    const float2* __restrict__ carry2,
    float2* __restrict__ y2)
{
    constexpr int L = T_ / NC;            // 32
    const int lane  = threadIdx.x & 63;   // feature pair 0..63
    const int slot  = threadIdx.x >> 6;   // 0..3 chunk slot
    const int cb    = blockIdx.x % (NC / 4);
    const int b     = blockIdx.x / (NC / 4);
    const int chunk = cb * 4 + slot;

    const float2 lsv = reinterpret_cast<const float2*>(log_s)[lane];
    const float s0 = expf(lsv.x), s1 = expf(lsv.y);
    const float a0 = 1.f - s0,   a1 = 1.f - s1;

    const float2 lav = reinterpret_cast<const float2*>(log_alpha)[lane];
    const float2 ldv = reinterpret_cast<const float2*>(log_delta)[lane];
    const float2 lrv = reinterpret_cast<const float2*>(log_r)[lane];
    const float na0 = -expf(lav.x), na1 = -expf(lav.y);
    const float d0 = expf(ldv.x),  d1 = expf(ldv.y);
    const float r0 = expf(lrv.x),  r1 = expf(lrv.y);

    const bool rhalf_lane = (r0 == 0.5f) && (r1 == 0.5f);
    const bool allhalf    = __all(rhalf_lane);

    const float dr0 = allhalf ? sqrtf(d0) : fpow(d0, r0);
    const float dr1 = allhalf ? sqrtf(d1) : fpow(d1, r1);

    const float2 c = carry2[((size_t)b * NC + chunk) * FH + lane];

    const size_t base = ((size_t)b * T_ + (size_t)chunk * L) * FH + lane;
    const float2* xp = x2 + base;
    float2*       yp = y2 + base;

    if (allhalf) {
        p3_loop<true >(xp, yp, L, c, s0, s1, a0, a1, na0, na1, d0, d1, r0, r1, dr0, dr1);
    } else {
        p3_loop<false>(xp, yp, L, c, s0, s1, a0, a1, na0, na1, d0, d1, r0, r1, dr0, dr1);
    }
}

template<int NC>
static void launch_all(const float* x, const float* state,
                       const float* log_s, const float* log_alpha,
                       const float* log_delta, const float* log_r,
                       float* y, float* new_state, float* ws, hipStream_t stream)
{
    const float4* x4      = (const float4*)x;
    const float4* state4  = (const float4*)state;
    float4* new_state4    = (float4*)new_state;
    float4* S4            = (float4*)ws;                 // B*NC*FG float4
    float4* carry4        = S4 + (size_t)B_ * NC * FG;   // B*NC*FG float4

    pcen_pass1<NC><<<dim3(B_ * (NC / 8)), dim3(256), 0, stream>>>(x4, log_s, S4);
    pcen_pass2<NC><<<dim3(B_), dim3(32), 0, stream>>>(state4, log_s, S4, carry4, new_state4);
    pcen_pass3<NC><<<dim3(B_ * (NC / 4)), dim3(256), 0, stream>>>(
        (const float2*)x, log_s, log_alpha, log_delta, log_r,
        (const float2*)carry4, (float2*)y);
}

extern "C" void kernel_launch(void* const* d_in, const int* in_sizes, int n_in,
                              void* d_out, int out_size, void* d_ws, size_t ws_size,
                              hipStream_t stream)
{
    const float* x         = (const float*)d_in[0];
    const float* state     = (const float*)d_in[1];
    const float* log_s     = (const float*)d_in[2];
    const float* log_alpha = (const float*)d_in[3];
    const float* log_delta = (const float*)d_in[4];
    const float* log_r     = (const float*)d_in[5];

    float* y         = (float*)d_out;
    float* new_state = y + (size_t)B_ * T_ * F_;

    // workspace need: 2 buffers of B*NC*F floats
    const size_t need256 = 2ull * B_ * 256 * F_ * sizeof(float);   // 8 MB
    const size_t need128 = 2ull * B_ * 128 * F_ * sizeof(float);   // 4 MB
    if (ws_size >= need256) {
        launch_all<256>(x, state, log_s, log_alpha, log_delta, log_r,
                        y, new_state, (float*)d_ws, stream);
    } else if (ws_size >= need128) {
        launch_all<128>(x, state, log_s, log_alpha, log_delta, log_r,
                        y, new_state, (float*)d_ws, stream);
    } else {
        launch_all<64>(x, state, log_s, log_alpha, log_delta, log_r,
                       y, new_state, (float*)d_ws, stream);
    }
}